// Round 1
// baseline (526.909 us; speedup 1.0000x reference)
//
#include <hip/hip_runtime.h>
#include <math.h>

// ---------------------------------------------------------------------------
// QuantumTransformerE2E on MI355X.
// Kernel 1: one block (128 thr) per chunk: conv+LN+chunk-attn+proj+6-qubit
//           circuit (statevector = 1 wave64, 1 complex amp per lane, gates
//           via __shfl_xor) + measurement + output proj/LN/SiLU -> cf (ws).
// Kernel 2: one block per batch: seq attention pool + classifier -> out.
// ---------------------------------------------------------------------------

constexpr int kNQ    = 6;
constexpr int kDM    = 128;
constexpr int kCH    = 4;
constexpr int kSEQ   = 2048;
constexpr int kCHUNK = 16;
constexpr int kBATCH = 128;
constexpr int kNCH   = kSEQ / kCHUNK;  // 128 chunks per batch row
constexpr int kNP    = 120;            // NFP + NMP
constexpr float kPI  = 3.14159265358979323846f;

// ---- quantum gate helpers: qubit w <-> bit (5-w) of the lane index --------

__device__ __forceinline__ void g_rx(float t, int w, int lane, float& ar, float& ai) {
  float s, c; __sincosf(0.5f * t, &s, &c);  // fast path ok? use precise:
  s = sinf(0.5f * t); c = cosf(0.5f * t);
  int m = 1 << (5 - w);
  float pr = __shfl_xor(ar, m, 64);
  float pi = __shfl_xor(ai, m, 64);
  float nr = fmaf(c, ar,  s * pi);
  float ni = fmaf(c, ai, -s * pr);
  ar = nr; ai = ni;
}

__device__ __forceinline__ void g_ry(float t, int w, int lane, float& ar, float& ai) {
  float s = sinf(0.5f * t), c = cosf(0.5f * t);
  int m = 1 << (5 - w);
  float pr = __shfl_xor(ar, m, 64);
  float pi = __shfl_xor(ai, m, 64);
  float sg = ((lane >> (5 - w)) & 1) ? s : -s;
  float nr = fmaf(c, ar, sg * pr);
  float ni = fmaf(c, ai, sg * pi);
  ar = nr; ai = ni;
}

__device__ __forceinline__ void g_rz(float t, int w, int lane, float& ar, float& ai) {
  float s = sinf(0.5f * t), c = cosf(0.5f * t);
  float sp = ((lane >> (5 - w)) & 1) ? s : -s;
  float nr = fmaf(ar, c, -ai * sp);
  float ni = fmaf(ar, sp,  ai * c);
  ar = nr; ai = ni;
}

__device__ __forceinline__ void g_crx(float t, int w0, int w1, int lane, float& ar, float& ai) {
  float s = sinf(0.5f * t), c = cosf(0.5f * t);
  int m = 1 << (5 - w1);
  float pr = __shfl_xor(ar, m, 64);
  float pi = __shfl_xor(ai, m, 64);
  if ((lane >> (5 - w0)) & 1) {
    float nr = fmaf(c, ar,  s * pi);
    float ni = fmaf(c, ai, -s * pr);
    ar = nr; ai = ni;
  }
}

__device__ __forceinline__ void apply_ansatz(const float* p, int lane, float& ar, float& ai) {
  for (int i = 0; i < kNQ; ++i) {
    g_rx(p[3 * i + 0], i, lane, ar, ai);
    g_ry(p[3 * i + 1], i, lane, ar, ai);
    g_rz(p[3 * i + 2], i, lane, ar, ai);
  }
  int off = 3 * kNQ;                       // 18
  for (int i = 0; i < kNQ; ++i) g_crx(p[off++], i, (i + 1) % kNQ, lane, ar, ai);
  for (int i = kNQ - 1; i >= 0; --i) g_crx(p[off++], i, (i + 5) % kNQ, lane, ar, ai);
}

// ---------------------------------------------------------------------------

__global__ __launch_bounds__(128) void k_chunk(
    const float* __restrict__ x,
    const float* __restrict__ conv_w, const float* __restrict__ conv_b,
    const float* __restrict__ ln1_g,  const float* __restrict__ ln1_b,
    const float* __restrict__ ca1_w,  const float* __restrict__ ca1_b,
    const float* __restrict__ ca2_w,  const float* __restrict__ ca2_b,
    const float* __restrict__ pp_w,   const float* __restrict__ pp_b,
    const float* __restrict__ ep_w,   const float* __restrict__ ep_b,
    const float* __restrict__ op_w,   const float* __restrict__ op_b,
    const float* __restrict__ ln2_g,  const float* __restrict__ ln2_b,
    float* __restrict__ cf)
{
  __shared__ float xs[kCH][kCHUNK + 2];      // conv input halo
  __shared__ float hbuf[kCHUNK][kDM + 1];    // pad 129 -> conflict-free
  __shared__ float hid[kCHUNK][33];          // pad 33
  __shared__ float scl[kCHUNK];
  __shared__ float mrow[kCHUNK], irow[kCHUNK];
  __shared__ float summ[kDM];
  __shared__ float apb[kNP];
  __shared__ float angb[kNQ];
  __shared__ float qv[3 * kNQ];
  __shared__ float red[4];

  const int tid   = threadIdx.x;
  const int chunk = blockIdx.x;
  const int b     = chunk >> 7;
  const int nc    = chunk & 127;
  const int t0    = nc * kCHUNK;
  const int d     = tid;

  // ---- stage x halo (4 ch x 18 pos) ----
  if (tid < kCH * (kCHUNK + 2)) {
    int ch  = tid / (kCHUNK + 2);
    int pos = tid % (kCHUNK + 2);
    int s   = t0 - 1 + pos;
    float v = 0.f;
    if (s >= 0 && s < kSEQ) v = x[(b * kCH + ch) * kSEQ + s];
    xs[ch][pos] = v;
  }
  __syncthreads();

  // ---- conv1d: thread d computes h[t][d] for all 16 t ----
  float w12[12];
  {
    const float4* cw = (const float4*)(conv_w + d * 12);  // 48B rows, 16B aligned
    float4 a0 = cw[0], a1 = cw[1], a2 = cw[2];
    w12[0] = a0.x; w12[1]  = a0.y; w12[2]  = a0.z; w12[3]  = a0.w;
    w12[4] = a1.x; w12[5]  = a1.y; w12[6]  = a1.z; w12[7]  = a1.w;
    w12[8] = a2.x; w12[9]  = a2.y; w12[10] = a2.z; w12[11] = a2.w;
  }
  float cb = conv_b[d];
  for (int t = 0; t < kCHUNK; ++t) {
    float acc = cb;
#pragma unroll
    for (int ch = 0; ch < kCH; ++ch)
#pragma unroll
      for (int k = 0; k < 3; ++k)
        acc = fmaf(xs[ch][t + k], w12[ch * 3 + k], acc);
    hbuf[t][d] = acc;
  }
  __syncthreads();

  // ---- LN1 stats (16 rows, one thread each) ----
  if (tid < kCHUNK) {
    float s1 = 0.f, s2 = 0.f;
    for (int dd = 0; dd < kDM; ++dd) { float v = hbuf[tid][dd]; s1 += v; s2 = fmaf(v, v, s2); }
    float m   = s1 * (1.f / kDM);
    float var = s2 * (1.f / kDM) - m * m;
    mrow[tid] = m;
    irow[tid] = rsqrtf(var + 1e-5f);
  }
  __syncthreads();

  {
    float g1 = ln1_g[d], b1 = ln1_b[d];
    for (int t = 0; t < kCHUNK; ++t)
      hbuf[t][d] = fmaf((hbuf[t][d] - mrow[t]) * irow[t], g1, b1);
  }
  __syncthreads();

  // ---- chunk attention hidden: tanh(h @ ca1_w + b) ----
  {
    int j  = tid & 31;
    int tg = tid >> 5;
    float bj = ca1_b[j];
    for (int pass = 0; pass < 4; ++pass) {
      int t = tg + pass * 4;
      float acc = bj;
      for (int dd = 0; dd < kDM; ++dd)
        acc = fmaf(hbuf[t][dd], ca1_w[dd * 32 + j], acc);
      hid[t][j] = tanhf(acc);
    }
  }
  __syncthreads();

  if (tid < kCHUNK) {
    float acc = ca2_b[0];
    for (int j = 0; j < 32; ++j) acc = fmaf(hid[tid][j], ca2_w[j], acc);
    scl[tid] = acc;
  }
  __syncthreads();

  // ---- softmax over 16 + weighted sum (redundant per-thread, no syncs) ----
  {
    float mx = -1e30f;
#pragma unroll
    for (int t = 0; t < kCHUNK; ++t) mx = fmaxf(mx, scl[t]);
    float wv[kCHUNK]; float ssum = 0.f;
#pragma unroll
    for (int t = 0; t < kCHUNK; ++t) { wv[t] = expf(scl[t] - mx); ssum += wv[t]; }
    float inv = 1.f / ssum;
    float acc = 0.f;
#pragma unroll
    for (int t = 0; t < kCHUNK; ++t) acc = fmaf(wv[t] * inv, hbuf[t][d], acc);
    summ[d] = acc;
  }
  __syncthreads();

  // ---- ap (120) and ang (6) projections ----
  if (tid < kNP) {
    float acc = pp_b[tid];
    for (int dd = 0; dd < kDM; ++dd) acc = fmaf(summ[dd], pp_w[dd * kNP + tid], acc);
    apb[tid] = acc;
  } else if (tid < kNP + kNQ) {
    int j = tid - kNP;
    float acc = ep_b[j];
    for (int dd = 0; dd < kDM; ++dd) acc = fmaf(summ[dd], ep_w[dd * kNQ + j], acc);
    angb[j] = tanhf(acc) * kPI;
  }
  __syncthreads();

  // ---- 6-qubit circuit: wave 0 only, 1 complex amplitude per lane ----
  if (tid < 64) {
    int lane = tid;
    float ar = (lane == 0) ? 1.f : 0.f;
    float ai = 0.f;
#pragma unroll
    for (int i = 0; i < kNQ; ++i) g_ry(angb[i], i, lane, ar, ai);
    apply_ansatz(apb +  0, lane, ar, ai);   // fp layer 1
    apply_ansatz(apb + 30, lane, ar, ai);   // fp layer 2
    apply_ansatz(apb + 60, lane, ar, ai);   // mp layer 1
    apply_ansatz(apb + 90, lane, ar, ai);   // mp layer 2

    // measurement: X_i, Y_i, Z_i
    for (int i = 0; i < kNQ; ++i) {
      int m = 1 << (5 - i);
      float pr = __shfl_xor(ar, m, 64);
      float pi = __shfl_xor(ai, m, 64);
      int bit = (lane >> (5 - i)) & 1;
      float nrm = fmaf(ar, ar, ai * ai);
      float abr, abi, zz;
      if (bit) { abr = 0.f; abi = 0.f; zz = -nrm; }
      else {
        abr = fmaf(ar, pr,  ai * pi);
        abi = fmaf(ar, pi, -ai * pr);
        zz  = nrm;
      }
      for (int o = 32; o; o >>= 1) {
        abr += __shfl_xor(abr, o, 64);
        abi += __shfl_xor(abi, o, 64);
        zz  += __shfl_xor(zz,  o, 64);
      }
      if (lane == 0) { qv[i] = 2.f * abr; qv[kNQ + i] = 2.f * abi; qv[2 * kNQ + i] = zz; }
    }
  }
  __syncthreads();

  // ---- cf = silu(LN2(q @ op_w + op_b)) ----
  {
    float acc = op_b[d];
#pragma unroll
    for (int j = 0; j < 3 * kNQ; ++j) acc = fmaf(qv[j], op_w[j * kDM + d], acc);
    float v = acc, v2 = acc * acc;
    for (int o = 32; o; o >>= 1) { v += __shfl_xor(v, o, 64); v2 += __shfl_xor(v2, o, 64); }
    int wv = tid >> 6;
    if ((tid & 63) == 0) { red[wv] = v; red[2 + wv] = v2; }
    __syncthreads();
    float s1 = red[0] + red[1], s2 = red[2] + red[3];
    float m   = s1 * (1.f / kDM);
    float var = s2 * (1.f / kDM) - m * m;
    float xn  = fmaf((acc - m) * rsqrtf(var + 1e-5f), ln2_g[d], ln2_b[d]);
    cf[chunk * kDM + d] = xn / (1.f + expf(-xn));
  }
}

// ---------------------------------------------------------------------------

__global__ __launch_bounds__(128) void k_head(
    const float* __restrict__ cf,
    const float* __restrict__ sa1_w, const float* __restrict__ sa1_b,
    const float* __restrict__ sa2_w, const float* __restrict__ sa2_b,
    const float* __restrict__ cl1_w, const float* __restrict__ cl1_b,
    const float* __restrict__ cl2_w, const float* __restrict__ cl2_b,
    float* __restrict__ out)
{
  __shared__ float hid[kNCH][33];
  __shared__ float scl[kNCH];
  __shared__ float wl[kNCH];
  __shared__ float rep[kDM];
  __shared__ float ul[64];

  const int b = blockIdx.x, tid = threadIdx.x;
  const float* cfb = cf + (size_t)b * kNCH * kDM;

  // hidden: 128 chunks x 32 hidden, 4096 dot-128s over 128 threads
  {
    int j = tid & 31;
    float bj = sa1_b[j];
    for (int k = 0; k < 32; ++k) {
      int nc = (tid >> 5) + k * 4;
      float acc = bj;
      for (int dd = 0; dd < kDM; ++dd)
        acc = fmaf(cfb[nc * kDM + dd], sa1_w[dd * 32 + j], acc);
      hid[nc][j] = tanhf(acc);
    }
  }
  __syncthreads();

  {
    float acc = sa2_b[0];
    for (int j = 0; j < 32; ++j) acc = fmaf(hid[tid][j], sa2_w[j], acc);
    scl[tid] = acc;
  }
  __syncthreads();

  {
    float mx = -1e30f;
    for (int t = 0; t < kNCH; ++t) mx = fmaxf(mx, scl[t]);
    wl[tid] = expf(scl[tid] - mx);
  }
  __syncthreads();

  {
    float ssum = 0.f;
    for (int t = 0; t < kNCH; ++t) ssum += wl[t];
    float inv = 1.f / ssum;
    float acc = 0.f;
    for (int ncc = 0; ncc < kNCH; ++ncc)
      acc = fmaf(wl[ncc] * inv, cfb[ncc * kDM + tid], acc);
    rep[tid] = acc;
  }
  __syncthreads();

  if (tid < 64) {
    float acc = cl1_b[tid];
    for (int dd = 0; dd < kDM; ++dd) acc = fmaf(rep[dd], cl1_w[dd * 64 + tid], acc);
    ul[tid] = acc / (1.f + expf(-acc));
  }
  __syncthreads();

  if (tid < 2) {
    float acc = cl2_b[tid];
    for (int j = 0; j < 64; ++j) acc = fmaf(ul[j], cl2_w[j * 2 + tid], acc);
    out[b * 2 + tid] = acc;
  }
}

// ---------------------------------------------------------------------------

extern "C" void kernel_launch(void* const* d_in, const int* in_sizes, int n_in,
                              void* d_out, int out_size, void* d_ws, size_t ws_size,
                              hipStream_t stream) {
  const float* x      = (const float*)d_in[0];
  const float* conv_w = (const float*)d_in[1];
  const float* conv_b = (const float*)d_in[2];
  const float* ln1_g  = (const float*)d_in[3];
  const float* ln1_b  = (const float*)d_in[4];
  const float* ca1_w  = (const float*)d_in[5];
  const float* ca1_b  = (const float*)d_in[6];
  const float* ca2_w  = (const float*)d_in[7];
  const float* ca2_b  = (const float*)d_in[8];
  const float* pp_w   = (const float*)d_in[9];
  const float* pp_b   = (const float*)d_in[10];
  const float* ep_w   = (const float*)d_in[11];
  const float* ep_b   = (const float*)d_in[12];
  const float* op_w   = (const float*)d_in[13];
  const float* op_b   = (const float*)d_in[14];
  const float* ln2_g  = (const float*)d_in[15];
  const float* ln2_b  = (const float*)d_in[16];
  const float* sa1_w  = (const float*)d_in[17];
  const float* sa1_b  = (const float*)d_in[18];
  const float* sa2_w  = (const float*)d_in[19];
  const float* sa2_b  = (const float*)d_in[20];
  const float* cl1_w  = (const float*)d_in[21];
  const float* cl1_b  = (const float*)d_in[22];
  const float* cl2_w  = (const float*)d_in[23];
  const float* cl2_b  = (const float*)d_in[24];
  float* out = (float*)d_out;
  float* cf  = (float*)d_ws;   // 16384 x 128 fp32 = 8 MB

  k_chunk<<<kBATCH * kNCH, 128, 0, stream>>>(
      x, conv_w, conv_b, ln1_g, ln1_b, ca1_w, ca1_b, ca2_w, ca2_b,
      pp_w, pp_b, ep_w, ep_b, op_w, op_b, ln2_g, ln2_b, cf);
  k_head<<<kBATCH, 128, 0, stream>>>(
      cf, sa1_w, sa1_b, sa2_w, sa2_b, cl1_w, cl1_b, cl2_w, cl2_b, out);
}

// Round 2
// 330.206 us; speedup vs baseline: 1.5957x; 1.5957x over previous
//
#include <hip/hip_runtime.h>
#include <math.h>

// ---------------------------------------------------------------------------
// QuantumTransformerE2E on MI355X — R2.
// k_chunk: one block (128 thr) per chunk. Gate trig precomputed in parallel
//          (126 sincos by 126 threads), circuit reads (c,s) pairs from LDS.
//          Attn GEMV register-blocked sub-split. LN stats via shfl reduction.
// k_scl:   one wave per (batch,chunk): seq-attention scores.
// k_pool:  one block per batch: softmax + pooled rep + classifier.
// ---------------------------------------------------------------------------

constexpr int kNQ    = 6;
constexpr int kDM    = 128;
constexpr int kCH    = 4;
constexpr int kSEQ   = 2048;
constexpr int kCHUNK = 16;
constexpr int kBATCH = 128;
constexpr int kNCH   = kSEQ / kCHUNK;  // 128
constexpr int kNP    = 120;
constexpr float kPI  = 3.14159265358979323846f;

// ---- gates: cs = (cos(t/2), sin(t/2)); qubit w <-> bit (5-w) of lane ------

__device__ __forceinline__ void g_rx(float2 cs, int w, int lane, float& ar, float& ai) {
  int m = 1 << (5 - w);
  float pr = __shfl_xor(ar, m, 64);
  float pi = __shfl_xor(ai, m, 64);
  float nr = fmaf(cs.x, ar,  cs.y * pi);
  float ni = fmaf(cs.x, ai, -cs.y * pr);
  ar = nr; ai = ni;
}

__device__ __forceinline__ void g_ry(float2 cs, int w, int lane, float& ar, float& ai) {
  int m = 1 << (5 - w);
  float pr = __shfl_xor(ar, m, 64);
  float pi = __shfl_xor(ai, m, 64);
  float sg = ((lane >> (5 - w)) & 1) ? cs.y : -cs.y;
  float nr = fmaf(cs.x, ar, sg * pr);
  float ni = fmaf(cs.x, ai, sg * pi);
  ar = nr; ai = ni;
}

__device__ __forceinline__ void g_rz(float2 cs, int w, int lane, float& ar, float& ai) {
  float sp = ((lane >> (5 - w)) & 1) ? cs.y : -cs.y;
  float nr = fmaf(ar, cs.x, -ai * sp);
  float ni = fmaf(ar, sp,  ai * cs.x);
  ar = nr; ai = ni;
}

__device__ __forceinline__ void g_crx(float2 cs, int w0, int w1, int lane, float& ar, float& ai) {
  int m = 1 << (5 - w1);
  float pr = __shfl_xor(ar, m, 64);
  float pi = __shfl_xor(ai, m, 64);
  if ((lane >> (5 - w0)) & 1) {
    float nr = fmaf(cs.x, ar,  cs.y * pi);
    float ni = fmaf(cs.x, ai, -cs.y * pr);
    ar = nr; ai = ni;
  }
}

__device__ __forceinline__ void apply_ansatz(const float2* cs, int lane, float& ar, float& ai) {
#pragma unroll
  for (int i = 0; i < kNQ; ++i) {
    g_rx(cs[3 * i + 0], i, lane, ar, ai);
    g_ry(cs[3 * i + 1], i, lane, ar, ai);
    g_rz(cs[3 * i + 2], i, lane, ar, ai);
  }
  int off = 3 * kNQ;
#pragma unroll
  for (int i = 0; i < kNQ; ++i) g_crx(cs[off++], i, (i + 1) % kNQ, lane, ar, ai);
#pragma unroll
  for (int i = kNQ - 1; i >= 0; --i) g_crx(cs[off++], i, (i + 5) % kNQ, lane, ar, ai);
}

// ---------------------------------------------------------------------------

__global__ __launch_bounds__(128) void k_chunk(
    const float* __restrict__ x,
    const float* __restrict__ conv_w, const float* __restrict__ conv_b,
    const float* __restrict__ ln1_g,  const float* __restrict__ ln1_b,
    const float* __restrict__ ca1_w,  const float* __restrict__ ca1_b,
    const float* __restrict__ ca2_w,  const float* __restrict__ ca2_b,
    const float* __restrict__ pp_w,   const float* __restrict__ pp_b,
    const float* __restrict__ ep_w,   const float* __restrict__ ep_b,
    const float* __restrict__ op_w,   const float* __restrict__ op_b,
    const float* __restrict__ ln2_g,  const float* __restrict__ ln2_b,
    float* __restrict__ cf)
{
  __shared__ float  xs[kCH][kCHUNK + 2];
  __shared__ float  hbuf[kCHUNK][132];     // rows 16B-aligned, stride 132
  __shared__ float  mrow[kCHUNK], irow[kCHUNK];
  __shared__ float  part[2][32][20];       // attn partials, stride 20
  __shared__ float  hid[kCHUNK][33];
  __shared__ float  scl[kCHUNK];
  __shared__ float  ew[kCHUNK];
  __shared__ float  summ[kDM];
  __shared__ float2 csb[6 + kNP];          // (cos,sin) of every half-angle
  __shared__ float  qv[3 * kNQ];
  __shared__ float  red[4];

  const int tid   = threadIdx.x;
  const int chunk = blockIdx.x;
  const int b     = chunk >> 7;
  const int nc    = chunk & 127;
  const int t0    = nc * kCHUNK;
  const int d     = tid;

  // ---- stage x halo ----
  if (tid < kCH * (kCHUNK + 2)) {
    int ch  = tid / (kCHUNK + 2);
    int pos = tid % (kCHUNK + 2);
    int s   = t0 - 1 + pos;
    float v = 0.f;
    if (s >= 0 && s < kSEQ) v = x[(b * kCH + ch) * kSEQ + s];
    xs[ch][pos] = v;
  }
  __syncthreads();

  // ---- conv1d into registers h[16] + raw LDS copy ----
  float w12[12];
  {
    const float4* cw = (const float4*)(conv_w + d * 12);
    float4 a0 = cw[0], a1 = cw[1], a2 = cw[2];
    w12[0] = a0.x; w12[1]  = a0.y; w12[2]  = a0.z; w12[3]  = a0.w;
    w12[4] = a1.x; w12[5]  = a1.y; w12[6]  = a1.z; w12[7]  = a1.w;
    w12[8] = a2.x; w12[9]  = a2.y; w12[10] = a2.z; w12[11] = a2.w;
  }
  float cb = conv_b[d];
  float h[kCHUNK];
#pragma unroll
  for (int t = 0; t < kCHUNK; ++t) {
    float acc = cb;
#pragma unroll
    for (int ch = 0; ch < kCH; ++ch)
#pragma unroll
      for (int k = 0; k < 3; ++k)
        acc = fmaf(xs[ch][t + k], w12[ch * 3 + k], acc);
    h[t] = acc;
    hbuf[t][d] = acc;
  }
  __syncthreads();

  // ---- LN1 stats: 8 lanes per row, shfl combine ----
  {
    int row = tid >> 3, k = tid & 7;
    const float4* rp = (const float4*)&hbuf[row][k * 16];
    float s1 = 0.f, s2 = 0.f;
#pragma unroll
    for (int q = 0; q < 4; ++q) {
      float4 v = rp[q];
      s1 += v.x + v.y + v.z + v.w;
      s2 = fmaf(v.x, v.x, s2); s2 = fmaf(v.y, v.y, s2);
      s2 = fmaf(v.z, v.z, s2); s2 = fmaf(v.w, v.w, s2);
    }
#pragma unroll
    for (int o = 1; o < 8; o <<= 1) {
      s1 += __shfl_xor(s1, o, 64);
      s2 += __shfl_xor(s2, o, 64);
    }
    if (k == 0) {
      float m = s1 * (1.f / kDM);
      mrow[row] = m;
      irow[row] = rsqrtf(s2 * (1.f / kDM) - m * m + 1e-5f);
    }
  }
  __syncthreads();

  // ---- LN1 apply (registers + LDS writeback) ----
  {
    float g1 = ln1_g[d], b1 = ln1_b[d];
#pragma unroll
    for (int t = 0; t < kCHUNK; ++t) {
      h[t] = fmaf((h[t] - mrow[t]) * irow[t], g1, b1);
      hbuf[t][d] = h[t];
    }
  }
  __syncthreads();

  // ---- attn hidden GEMV: sub-split over dd, weights in registers ----
  {
    int j = tid & 31, sub = tid >> 5;       // sub 0..3 -> dd slice of 32
    float wreg[32];
    const float* wp = ca1_w + (sub * 32) * 32 + j;
#pragma unroll
    for (int k = 0; k < 32; ++k) wreg[k] = wp[k * 32];
    float p[kCHUNK];
#pragma unroll
    for (int t = 0; t < kCHUNK; ++t) {
      const float4* hp = (const float4*)&hbuf[t][sub * 32];
      float acc = 0.f;
#pragma unroll
      for (int q = 0; q < 8; ++q) {
        float4 v = hp[q];
        acc = fmaf(v.x, wreg[q * 4 + 0], acc);
        acc = fmaf(v.y, wreg[q * 4 + 1], acc);
        acc = fmaf(v.z, wreg[q * 4 + 2], acc);
        acc = fmaf(v.w, wreg[q * 4 + 3], acc);
      }
      p[t] = acc;
    }
#pragma unroll
    for (int t = 0; t < kCHUNK; ++t) p[t] += __shfl_xor(p[t], 32, 64);
    if ((sub & 1) == 0) {                   // lanes 0..31 of each wave
      float4* pp = (float4*)&part[sub >> 1][j][0];
      pp[0] = make_float4(p[0],  p[1],  p[2],  p[3]);
      pp[1] = make_float4(p[4],  p[5],  p[6],  p[7]);
      pp[2] = make_float4(p[8],  p[9],  p[10], p[11]);
      pp[3] = make_float4(p[12], p[13], p[14], p[15]);
    }
  }
  __syncthreads();

  // ---- hid = tanh(part0+part1+bias): 4 t per thread ----
  {
    int j2 = tid & 31, tq = tid >> 5;
    float bj = ca1_b[j2];
#pragma unroll
    for (int i = 0; i < 4; ++i) {
      int t = tq * 4 + i;
      hid[t][j2] = tanhf(part[0][j2][t] + part[1][j2][t] + bj);
    }
  }
  __syncthreads();

  // ---- ca2 -> scores ----
  if (tid < kCHUNK) {
    float acc = ca2_b[0];
#pragma unroll
    for (int j = 0; j < 32; ++j) acc = fmaf(hid[tid][j], ca2_w[j], acc);
    scl[tid] = acc;
  }
  __syncthreads();

  // ---- softmax weights (16 threads, 1 exp each) ----
  if (tid < kCHUNK) {
    float mx = -1e30f;
#pragma unroll
    for (int t = 0; t < kCHUNK; ++t) mx = fmaxf(mx, scl[t]);
    ew[tid] = expf(scl[tid] - mx);
  }
  __syncthreads();

  // ---- weighted sum from registers ----
  {
    float ssum = 0.f;
#pragma unroll
    for (int t = 0; t < kCHUNK; ++t) ssum += ew[t];
    float inv = 1.f / ssum;
    float acc = 0.f;
#pragma unroll
    for (int t = 0; t < kCHUNK; ++t) acc = fmaf(ew[t] * inv, h[t], acc);
    summ[d] = acc;
  }
  __syncthreads();

  // ---- projections + parallel sincos of half-angles ----
  if (tid < kNP) {
    float acc = pp_b[tid];
    for (int dd = 0; dd < kDM; ++dd) acc = fmaf(summ[dd], pp_w[dd * kNP + tid], acc);
    float s, c; sincosf(0.5f * acc, &s, &c);
    csb[6 + tid] = make_float2(c, s);
  } else if (tid < kNP + kNQ) {
    int jj = tid - kNP;
    float acc = ep_b[jj];
    for (int dd = 0; dd < kDM; ++dd) acc = fmaf(summ[dd], ep_w[dd * kNQ + jj], acc);
    float a = tanhf(acc) * kPI;
    float s, c; sincosf(0.5f * a, &s, &c);
    csb[jj] = make_float2(c, s);
  }
  __syncthreads();

  // ---- 6-qubit circuit on wave 0, trig from LDS ----
  if (tid < 64) {
    int lane = tid;
    float ar = (lane == 0) ? 1.f : 0.f;
    float ai = 0.f;
#pragma unroll
    for (int i = 0; i < kNQ; ++i) g_ry(csb[i], i, lane, ar, ai);
    apply_ansatz(csb + 6,      lane, ar, ai);  // fp layer 1
    apply_ansatz(csb + 6 + 30, lane, ar, ai);  // fp layer 2
    apply_ansatz(csb + 6 + 60, lane, ar, ai);  // mp layer 1
    apply_ansatz(csb + 6 + 90, lane, ar, ai);  // mp layer 2

    // measurement
#pragma unroll
    for (int i = 0; i < kNQ; ++i) {
      int m = 1 << (5 - i);
      float pr = __shfl_xor(ar, m, 64);
      float pi = __shfl_xor(ai, m, 64);
      int bit = (lane >> (5 - i)) & 1;
      float nrm = fmaf(ar, ar, ai * ai);
      float abr, abi, zz;
      if (bit) { abr = 0.f; abi = 0.f; zz = -nrm; }
      else {
        abr = fmaf(ar, pr,  ai * pi);
        abi = fmaf(ar, pi, -ai * pr);
        zz  = nrm;
      }
#pragma unroll
      for (int o = 32; o; o >>= 1) {
        abr += __shfl_xor(abr, o, 64);
        abi += __shfl_xor(abi, o, 64);
        zz  += __shfl_xor(zz,  o, 64);
      }
      if (lane == 0) { qv[i] = 2.f * abr; qv[kNQ + i] = 2.f * abi; qv[2 * kNQ + i] = zz; }
    }
  }
  __syncthreads();

  // ---- cf = silu(LN2(q @ op_w + op_b)) ----
  {
    float acc = op_b[d];
#pragma unroll
    for (int j = 0; j < 3 * kNQ; ++j) acc = fmaf(qv[j], op_w[j * kDM + d], acc);
    float v = acc, v2 = acc * acc;
#pragma unroll
    for (int o = 32; o; o >>= 1) { v += __shfl_xor(v, o, 64); v2 += __shfl_xor(v2, o, 64); }
    int wv = tid >> 6;
    if ((tid & 63) == 0) { red[wv] = v; red[2 + wv] = v2; }
    __syncthreads();
    float s1 = red[0] + red[1], s2 = red[2] + red[3];
    float m   = s1 * (1.f / kDM);
    float var = s2 * (1.f / kDM) - m * m;
    float xn  = fmaf((acc - m) * rsqrtf(var + 1e-5f), ln2_g[d], ln2_b[d]);
    cf[chunk * kDM + d] = xn / (1.f + expf(-xn));
  }
}

// ---------------------------------------------------------------------------
// k_scl: one wave per (batch,chunk) -> seq-attention score scl[b*128+nc]

__global__ __launch_bounds__(256) void k_scl(
    const float* __restrict__ cf,
    const float* __restrict__ sa1_w, const float* __restrict__ sa1_b,
    const float* __restrict__ sa2_w, const float* __restrict__ sa2_b,
    float* __restrict__ scl)
{
  int tid  = threadIdx.x;
  int wid  = tid >> 6, lane = tid & 63;
  int pair = blockIdx.x * 4 + wid;           // (b*128 + nc)
  int j = lane & 31, hh = lane >> 5;

  const float4* row = (const float4*)(cf + (size_t)pair * kDM + hh * 64);
  const float*  wp  = sa1_w + (hh * 64) * 32 + j;
  float acc = 0.f;
#pragma unroll
  for (int q = 0; q < 16; ++q) {
    float4 v = row[q];
    acc = fmaf(v.x, wp[(q * 4 + 0) * 32], acc);
    acc = fmaf(v.y, wp[(q * 4 + 1) * 32], acc);
    acc = fmaf(v.z, wp[(q * 4 + 2) * 32], acc);
    acc = fmaf(v.w, wp[(q * 4 + 3) * 32], acc);
  }
  acc += __shfl_xor(acc, 32, 64);
  float hv = tanhf(acc + sa1_b[j]);
  float v  = hv * sa2_w[j];
#pragma unroll
  for (int o = 16; o; o >>= 1) v += __shfl_xor(v, o, 64);
  if (lane == 0) scl[pair] = v + sa2_b[0];
}

// ---------------------------------------------------------------------------
// k_pool: one block per batch: softmax over 128 + pooled rep + classifier

__global__ __launch_bounds__(128) void k_pool(
    const float* __restrict__ cf, const float* __restrict__ scl,
    const float* __restrict__ cl1_w, const float* __restrict__ cl1_b,
    const float* __restrict__ cl2_w, const float* __restrict__ cl2_b,
    float* __restrict__ out)
{
  __shared__ float wl[kNCH];
  __shared__ float rep[kDM];
  __shared__ float ul[64];
  __shared__ float red2[4];

  int b = blockIdx.x, tid = threadIdx.x;
  float s = scl[b * kNCH + tid];
  float mx = s;
#pragma unroll
  for (int o = 32; o; o >>= 1) mx = fmaxf(mx, __shfl_xor(mx, o, 64));
  if ((tid & 63) == 0) red2[tid >> 6] = mx;
  __syncthreads();
  mx = fmaxf(red2[0], red2[1]);
  float e = expf(s - mx);
  float se = e;
#pragma unroll
  for (int o = 32; o; o >>= 1) se += __shfl_xor(se, o, 64);
  if ((tid & 63) == 0) red2[2 + (tid >> 6)] = se;
  wl[tid] = e;
  __syncthreads();
  float inv = 1.f / (red2[2] + red2[3]);

  const float* cfb = cf + (size_t)b * kNCH * kDM;
  float acc = 0.f;
  for (int ncc = 0; ncc < kNCH; ++ncc)
    acc = fmaf(wl[ncc] * inv, cfb[ncc * kDM + tid], acc);
  rep[tid] = acc;
  __syncthreads();

  if (tid < 64) {
    float a2 = cl1_b[tid];
    const float4* rp = (const float4*)rep;
#pragma unroll
    for (int q = 0; q < 32; ++q) {
      float4 v = rp[q];
      a2 = fmaf(v.x, cl1_w[(q * 4 + 0) * 64 + tid], a2);
      a2 = fmaf(v.y, cl1_w[(q * 4 + 1) * 64 + tid], a2);
      a2 = fmaf(v.z, cl1_w[(q * 4 + 2) * 64 + tid], a2);
      a2 = fmaf(v.w, cl1_w[(q * 4 + 3) * 64 + tid], a2);
    }
    ul[tid] = a2 / (1.f + expf(-a2));
  }
  __syncthreads();

  if (tid < 2) {
    float a3 = cl2_b[tid];
#pragma unroll
    for (int k = 0; k < 64; ++k) a3 = fmaf(ul[k], cl2_w[k * 2 + tid], a3);
    out[b * 2 + tid] = a3;
  }
}

// ---------------------------------------------------------------------------

extern "C" void kernel_launch(void* const* d_in, const int* in_sizes, int n_in,
                              void* d_out, int out_size, void* d_ws, size_t ws_size,
                              hipStream_t stream) {
  const float* x      = (const float*)d_in[0];
  const float* conv_w = (const float*)d_in[1];
  const float* conv_b = (const float*)d_in[2];
  const float* ln1_g  = (const float*)d_in[3];
  const float* ln1_b  = (const float*)d_in[4];
  const float* ca1_w  = (const float*)d_in[5];
  const float* ca1_b  = (const float*)d_in[6];
  const float* ca2_w  = (const float*)d_in[7];
  const float* ca2_b  = (const float*)d_in[8];
  const float* pp_w   = (const float*)d_in[9];
  const float* pp_b   = (const float*)d_in[10];
  const float* ep_w   = (const float*)d_in[11];
  const float* ep_b   = (const float*)d_in[12];
  const float* op_w   = (const float*)d_in[13];
  const float* op_b   = (const float*)d_in[14];
  const float* ln2_g  = (const float*)d_in[15];
  const float* ln2_b  = (const float*)d_in[16];
  const float* sa1_w  = (const float*)d_in[17];
  const float* sa1_b  = (const float*)d_in[18];
  const float* sa2_w  = (const float*)d_in[19];
  const float* sa2_b  = (const float*)d_in[20];
  const float* cl1_w  = (const float*)d_in[21];
  const float* cl1_b  = (const float*)d_in[22];
  const float* cl2_w  = (const float*)d_in[23];
  const float* cl2_b  = (const float*)d_in[24];
  float* out = (float*)d_out;
  float* cf  = (float*)d_ws;                               // 16384*128 f32 = 8 MB
  float* scl = (float*)d_ws + (size_t)kBATCH * kNCH * kDM; // 16384 f32

  k_chunk<<<kBATCH * kNCH, 128, 0, stream>>>(
      x, conv_w, conv_b, ln1_g, ln1_b, ca1_w, ca1_b, ca2_w, ca2_b,
      pp_w, pp_b, ep_w, ep_b, op_w, op_b, ln2_g, ln2_b, cf);
  k_scl<<<(kBATCH * kNCH) / 4, 256, 0, stream>>>(
      cf, sa1_w, sa1_b, sa2_w, sa2_b, scl);
  k_pool<<<kBATCH, 128, 0, stream>>>(
      cf, scl, cl1_w, cl1_b, cl2_w, cl2_b, out);
}

// Round 3
// 313.416 us; speedup vs baseline: 1.6812x; 1.0536x over previous
//
#include <hip/hip_runtime.h>
#include <math.h>

// ---------------------------------------------------------------------------
// QuantumTransformerE2E on MI355X — R3.
// k_chunk: occupancy-focused rewrite: 10.6 KB LDS (lifetime-overlaid union),
//          wave0-register attention finish (no hid/scl/ew arrays, -3 barriers),
//          conflict-free part[16][32], rotated GEMV reads, native-math
//          transcendentals, op_w prefetch across the circuit barrier.
// k_scl:   one wave per (batch,chunk): seq-attention scores.
// k_pool:  per-batch softmax + pooled rep (4 indep accumulators) + classifier.
// ---------------------------------------------------------------------------

constexpr int kNQ    = 6;
constexpr int kDM    = 128;
constexpr int kCH    = 4;
constexpr int kSEQ   = 2048;
constexpr int kCHUNK = 16;
constexpr int kBATCH = 128;
constexpr int kNCH   = kSEQ / kCHUNK;  // 128
constexpr int kNP    = 120;
constexpr float kPI  = 3.14159265358979323846f;

__device__ __forceinline__ float fast_tanh(float x) {
  float e = __expf(-2.f * fabsf(x));
  float r = (1.f - e) * __builtin_amdgcn_rcpf(1.f + e);
  return copysignf(r, x);
}

__device__ __forceinline__ float fast_silu(float x) {
  return x * __builtin_amdgcn_rcpf(1.f + __expf(-x));
}

// ---- gates: cs = (cos(t/2), sin(t/2)); qubit w <-> bit (5-w) of lane ------

__device__ __forceinline__ void g_rx(float2 cs, int w, int lane, float& ar, float& ai) {
  int m = 1 << (5 - w);
  float pr = __shfl_xor(ar, m, 64);
  float pi = __shfl_xor(ai, m, 64);
  float nr = fmaf(cs.x, ar,  cs.y * pi);
  float ni = fmaf(cs.x, ai, -cs.y * pr);
  ar = nr; ai = ni;
}

__device__ __forceinline__ void g_ry(float2 cs, int w, int lane, float& ar, float& ai) {
  int m = 1 << (5 - w);
  float pr = __shfl_xor(ar, m, 64);
  float pi = __shfl_xor(ai, m, 64);
  float sg = ((lane >> (5 - w)) & 1) ? cs.y : -cs.y;
  float nr = fmaf(cs.x, ar, sg * pr);
  float ni = fmaf(cs.x, ai, sg * pi);
  ar = nr; ai = ni;
}

__device__ __forceinline__ void g_rz(float2 cs, int w, int lane, float& ar, float& ai) {
  float sp = ((lane >> (5 - w)) & 1) ? cs.y : -cs.y;
  float nr = fmaf(ar, cs.x, -ai * sp);
  float ni = fmaf(ar, sp,  ai * cs.x);
  ar = nr; ai = ni;
}

__device__ __forceinline__ void g_crx(float2 cs, int w0, int w1, int lane, float& ar, float& ai) {
  int m = 1 << (5 - w1);
  float pr = __shfl_xor(ar, m, 64);
  float pi = __shfl_xor(ai, m, 64);
  if ((lane >> (5 - w0)) & 1) {
    float nr = fmaf(cs.x, ar,  cs.y * pi);
    float ni = fmaf(cs.x, ai, -cs.y * pr);
    ar = nr; ai = ni;
  }
}

__device__ __forceinline__ void apply_ansatz(const float2* cs, int lane, float& ar, float& ai) {
#pragma unroll
  for (int i = 0; i < kNQ; ++i) {
    g_rx(cs[3 * i + 0], i, lane, ar, ai);
    g_ry(cs[3 * i + 1], i, lane, ar, ai);
    g_rz(cs[3 * i + 2], i, lane, ar, ai);
  }
  int off = 3 * kNQ;
#pragma unroll
  for (int i = 0; i < kNQ; ++i) g_crx(cs[off++], i, (i + 1) % kNQ, lane, ar, ai);
#pragma unroll
  for (int i = kNQ - 1; i >= 0; --i) g_crx(cs[off++], i, (i + 5) % kNQ, lane, ar, ai);
}

// ---------------------------------------------------------------------------

__global__ __launch_bounds__(128, 6) void k_chunk(
    const float* __restrict__ x,
    const float* __restrict__ conv_w, const float* __restrict__ conv_b,
    const float* __restrict__ ln1_g,  const float* __restrict__ ln1_b,
    const float* __restrict__ ca1_w,  const float* __restrict__ ca1_b,
    const float* __restrict__ ca2_w,  const float* __restrict__ ca2_b,
    const float* __restrict__ pp_w,   const float* __restrict__ pp_b,
    const float* __restrict__ ep_w,   const float* __restrict__ ep_b,
    const float* __restrict__ op_w,   const float* __restrict__ op_b,
    const float* __restrict__ ln2_g,  const float* __restrict__ ln2_b,
    float* __restrict__ cf)
{
  __shared__ float hbuf[kCHUNK][132];        // 8448 B, rows 16B-aligned
  __shared__ __align__(16) float Bu[512];    // 2048 B overlaid union region
  __shared__ float mrow[kCHUNK], irow[kCHUNK];
  __shared__ float red[4];

  // union views (disjoint lifetimes):
  float (*xs)[kCHUNK + 2] = (float(*)[kCHUNK + 2])Bu;  // [4][18], conv halo
  float (*part)[32]       = (float(*)[32])Bu;          // [16][32], GEMV partials
  float*  summ = Bu;                                   // [128]
  float*  wl   = Bu + 128;                             // [16]  (16B aligned)
  float*  qv   = Bu + 144;                             // [18]
  float2* csb  = (float2*)(Bu + 164);                  // [126] (8B aligned)

  const int tid   = threadIdx.x;
  const int chunk = blockIdx.x;
  const int b     = chunk >> 7;
  const int nc    = chunk & 127;
  const int t0    = nc * kCHUNK;
  const int d     = tid;
  const int j     = tid & 31;
  const int sub   = tid >> 5;                // 0..3; wave0: 0,1  wave1: 2,3

  // ---- early global loads (in flight through conv/LN) ----
  float w12[12];
  {
    const float4* cw = (const float4*)(conv_w + d * 12);
    float4 a0 = cw[0], a1 = cw[1], a2 = cw[2];
    w12[0] = a0.x; w12[1]  = a0.y; w12[2]  = a0.z; w12[3]  = a0.w;
    w12[4] = a1.x; w12[5]  = a1.y; w12[6]  = a1.z; w12[7]  = a1.w;
    w12[8] = a2.x; w12[9]  = a2.y; w12[10] = a2.z; w12[11] = a2.w;
  }
  float cb = conv_b[d];
  float wreg[32];
  {
    const float* wp = ca1_w + (sub * 32) * 32 + j;
#pragma unroll
    for (int k = 0; k < 32; ++k) wreg[k] = wp[k * 32];
  }
  float g1 = ln1_g[d], b1 = ln1_b[d];

  // ---- stage x halo ----
  if (tid < kCH * (kCHUNK + 2)) {
    int ch  = tid / (kCHUNK + 2);
    int pos = tid % (kCHUNK + 2);
    int s   = t0 - 1 + pos;
    float v = 0.f;
    if (s >= 0 && s < kSEQ) v = x[(b * kCH + ch) * kSEQ + s];
    xs[ch][pos] = v;
  }
  __syncthreads();

  // ---- conv1d -> hbuf ----
#pragma unroll
  for (int t = 0; t < kCHUNK; ++t) {
    float acc = cb;
#pragma unroll
    for (int ch = 0; ch < kCH; ++ch)
#pragma unroll
      for (int k = 0; k < 3; ++k)
        acc = fmaf(xs[ch][t + k], w12[ch * 3 + k], acc);
    hbuf[t][d] = acc;
  }
  __syncthreads();

  // ---- LN1 stats: 8 lanes per row, shfl combine ----
  {
    int row = tid >> 3, k = tid & 7;
    const float4* rp = (const float4*)&hbuf[row][k * 16];
    float s1 = 0.f, s2 = 0.f;
#pragma unroll
    for (int q = 0; q < 4; ++q) {
      float4 v = rp[q];
      s1 += v.x + v.y + v.z + v.w;
      s2 = fmaf(v.x, v.x, s2); s2 = fmaf(v.y, v.y, s2);
      s2 = fmaf(v.z, v.z, s2); s2 = fmaf(v.w, v.w, s2);
    }
#pragma unroll
    for (int o = 1; o < 8; o <<= 1) {
      s1 += __shfl_xor(s1, o, 64);
      s2 += __shfl_xor(s2, o, 64);
    }
    if (k == 0) {
      float m = s1 * (1.f / kDM);
      mrow[row] = m;
      irow[row] = rsqrtf(s2 * (1.f / kDM) - m * m + 1e-5f);
    }
  }
  __syncthreads();

  // ---- LN1 apply in place ----
#pragma unroll
  for (int t = 0; t < kCHUNK; ++t)
    hbuf[t][d] = fmaf((hbuf[t][d] - mrow[t]) * irow[t], g1, b1);
  __syncthreads();

  // ---- attn hidden GEMV: sub-split over dd, rotated reads ----
  float p[kCHUNK];
#pragma unroll
  for (int t = 0; t < kCHUNK; ++t) {
    float acc = 0.f;
#pragma unroll
    for (int qq = 0; qq < 8; ++qq) {
      int q = (qq + 2 * sub) & 7;           // bank-quad rotation per sub
      float4 v = *(const float4*)&hbuf[t][sub * 32 + q * 4];
      acc = fmaf(v.x, wreg[q * 4 + 0], acc);
      acc = fmaf(v.y, wreg[q * 4 + 1], acc);
      acc = fmaf(v.z, wreg[q * 4 + 2], acc);
      acc = fmaf(v.w, wreg[q * 4 + 3], acc);
    }
    p[t] = acc;
  }
#pragma unroll
  for (int t = 0; t < kCHUNK; ++t) p[t] += __shfl_xor(p[t], 32, 64);
  if (sub == 2) {                            // wave1 lower half -> LDS
#pragma unroll
    for (int t = 0; t < kCHUNK; ++t) part[t][j] = p[t];
  }
  __syncthreads();

  // ---- wave0: hid, scores, softmax — all in registers ----
  if (tid < 64) {
    float bj = ca1_b[j];
    float w2 = ca2_w[j];
#pragma unroll
    for (int t = 0; t < kCHUNK; ++t)
      p[t] = fast_tanh(p[t] + part[t][j] + bj) * w2;
#pragma unroll
    for (int o = 16; o; o >>= 1)
#pragma unroll
      for (int t = 0; t < kCHUNK; ++t) p[t] += __shfl_xor(p[t], o, 64);
    float mx = p[0];
#pragma unroll
    for (int t = 1; t < kCHUNK; ++t) mx = fmaxf(mx, p[t]);
    float e[kCHUNK], ssum = 0.f;
#pragma unroll
    for (int t = 0; t < kCHUNK; ++t) { e[t] = __expf(p[t] - mx); ssum += e[t]; }
    float inv = 1.f / ssum;
    if (tid == 0) {
      float4* w4 = (float4*)wl;
      w4[0] = make_float4(e[0]  * inv, e[1]  * inv, e[2]  * inv, e[3]  * inv);
      w4[1] = make_float4(e[4]  * inv, e[5]  * inv, e[6]  * inv, e[7]  * inv);
      w4[2] = make_float4(e[8]  * inv, e[9]  * inv, e[10] * inv, e[11] * inv);
      w4[3] = make_float4(e[12] * inv, e[13] * inv, e[14] * inv, e[15] * inv);
    }
  }
  __syncthreads();

  // ---- weighted sum -> summ ----
  {
    float acc = 0.f;
    const float4* w4 = (const float4*)wl;
#pragma unroll
    for (int tq = 0; tq < 4; ++tq) {
      float4 wv = w4[tq];
      acc = fmaf(wv.x, hbuf[tq * 4 + 0][d], acc);
      acc = fmaf(wv.y, hbuf[tq * 4 + 1][d], acc);
      acc = fmaf(wv.z, hbuf[tq * 4 + 2][d], acc);
      acc = fmaf(wv.w, hbuf[tq * 4 + 3][d], acc);
    }
    summ[d] = acc;                           // disjoint from wl -> no hazard
  }
  __syncthreads();

  // ---- projections + parallel sincos (native) ----
  if (tid < kNP) {
    float acc = pp_b[tid];
    const float4* s4 = (const float4*)summ;
#pragma unroll 8
    for (int q = 0; q < 32; ++q) {
      float4 v = s4[q];
      acc = fmaf(v.x, pp_w[(q * 4 + 0) * kNP + tid], acc);
      acc = fmaf(v.y, pp_w[(q * 4 + 1) * kNP + tid], acc);
      acc = fmaf(v.z, pp_w[(q * 4 + 2) * kNP + tid], acc);
      acc = fmaf(v.w, pp_w[(q * 4 + 3) * kNP + tid], acc);
    }
    csb[6 + tid] = make_float2(__cosf(0.5f * acc), __sinf(0.5f * acc));
  } else if (tid < kNP + kNQ) {
    int jj = tid - kNP;
    float acc = ep_b[jj];
    for (int dd = 0; dd < kDM; ++dd) acc = fmaf(summ[dd], ep_w[dd * kNQ + jj], acc);
    float a = fast_tanh(acc) * kPI;
    csb[jj] = make_float2(__cosf(0.5f * a), __sinf(0.5f * a));
  }

  // ---- epilogue prefetch (flies during circuit barrier/idle) ----
  float ow[3 * kNQ];
#pragma unroll
  for (int jj = 0; jj < 3 * kNQ; ++jj) ow[jj] = op_w[jj * kDM + d];
  float g2 = ln2_g[d], b2 = ln2_b[d], ob = op_b[d];
  __syncthreads();

  // ---- 6-qubit circuit on wave 0 ----
  if (tid < 64) {
    int lane = tid;
    float ar = (lane == 0) ? 1.f : 0.f;
    float ai = 0.f;
#pragma unroll
    for (int i = 0; i < kNQ; ++i) g_ry(csb[i], i, lane, ar, ai);
    apply_ansatz(csb + 6,      lane, ar, ai);
    apply_ansatz(csb + 6 + 30, lane, ar, ai);
    apply_ansatz(csb + 6 + 60, lane, ar, ai);
    apply_ansatz(csb + 6 + 90, lane, ar, ai);

#pragma unroll
    for (int i = 0; i < kNQ; ++i) {
      int m = 1 << (5 - i);
      float pr = __shfl_xor(ar, m, 64);
      float pi = __shfl_xor(ai, m, 64);
      int bit = (lane >> (5 - i)) & 1;
      float nrm = fmaf(ar, ar, ai * ai);
      float abr, abi, zz;
      if (bit) { abr = 0.f; abi = 0.f; zz = -nrm; }
      else {
        abr = fmaf(ar, pr,  ai * pi);
        abi = fmaf(ar, pi, -ai * pr);
        zz  = nrm;
      }
#pragma unroll
      for (int o = 32; o; o >>= 1) {
        abr += __shfl_xor(abr, o, 64);
        abi += __shfl_xor(abi, o, 64);
        zz  += __shfl_xor(zz,  o, 64);
      }
      if (lane == 0) { qv[i] = 2.f * abr; qv[kNQ + i] = 2.f * abi; qv[2 * kNQ + i] = zz; }
    }
  }
  __syncthreads();

  // ---- cf = silu(LN2(q @ op_w + op_b)) ----
  {
    float acc = ob;
#pragma unroll
    for (int jj = 0; jj < 3 * kNQ; ++jj) acc = fmaf(qv[jj], ow[jj], acc);
    float v = acc, v2 = acc * acc;
#pragma unroll
    for (int o = 32; o; o >>= 1) { v += __shfl_xor(v, o, 64); v2 += __shfl_xor(v2, o, 64); }
    int wv = tid >> 6;
    if ((tid & 63) == 0) { red[wv] = v; red[2 + wv] = v2; }
    __syncthreads();
    float s1 = red[0] + red[1], s2 = red[2] + red[3];
    float m   = s1 * (1.f / kDM);
    float var = s2 * (1.f / kDM) - m * m;
    float xn  = fmaf((acc - m) * rsqrtf(var + 1e-5f), g2, b2);
    cf[chunk * kDM + d] = fast_silu(xn);
  }
}

// ---------------------------------------------------------------------------
// k_scl: one wave per (batch,chunk) -> seq-attention score scl[b*128+nc]

__global__ __launch_bounds__(256) void k_scl(
    const float* __restrict__ cf,
    const float* __restrict__ sa1_w, const float* __restrict__ sa1_b,
    const float* __restrict__ sa2_w, const float* __restrict__ sa2_b,
    float* __restrict__ scl)
{
  int tid  = threadIdx.x;
  int wid  = tid >> 6, lane = tid & 63;
  int pair = blockIdx.x * 4 + wid;           // (b*128 + nc)
  int j = lane & 31, hh = lane >> 5;

  const float4* row = (const float4*)(cf + (size_t)pair * kDM + hh * 64);
  const float*  wp  = sa1_w + (hh * 64) * 32 + j;
  float acc = 0.f;
#pragma unroll
  for (int q = 0; q < 16; ++q) {
    float4 v = row[q];
    acc = fmaf(v.x, wp[(q * 4 + 0) * 32], acc);
    acc = fmaf(v.y, wp[(q * 4 + 1) * 32], acc);
    acc = fmaf(v.z, wp[(q * 4 + 2) * 32], acc);
    acc = fmaf(v.w, wp[(q * 4 + 3) * 32], acc);
  }
  acc += __shfl_xor(acc, 32, 64);
  float hv = fast_tanh(acc + sa1_b[j]);
  float v  = hv * sa2_w[j];
#pragma unroll
  for (int o = 16; o; o >>= 1) v += __shfl_xor(v, o, 64);
  if (lane == 0) scl[pair] = v + sa2_b[0];
}

// ---------------------------------------------------------------------------
// k_pool: one block per batch: softmax over 128 + pooled rep + classifier

__global__ __launch_bounds__(128) void k_pool(
    const float* __restrict__ cf, const float* __restrict__ scl,
    const float* __restrict__ cl1_w, const float* __restrict__ cl1_b,
    const float* __restrict__ cl2_w, const float* __restrict__ cl2_b,
    float* __restrict__ out)
{
  __shared__ float wl[kNCH];
  __shared__ float rep[kDM];
  __shared__ float ul[64];
  __shared__ float red2[4];

  int b = blockIdx.x, tid = threadIdx.x;
  float s = scl[b * kNCH + tid];
  float mx = s;
#pragma unroll
  for (int o = 32; o; o >>= 1) mx = fmaxf(mx, __shfl_xor(mx, o, 64));
  if ((tid & 63) == 0) red2[tid >> 6] = mx;
  __syncthreads();
  mx = fmaxf(red2[0], red2[1]);
  float e = __expf(s - mx);
  float se = e;
#pragma unroll
  for (int o = 32; o; o >>= 1) se += __shfl_xor(se, o, 64);
  if ((tid & 63) == 0) red2[2 + (tid >> 6)] = se;
  wl[tid] = e;
  __syncthreads();
  float inv = 1.f / (red2[2] + red2[3]);

  const float* cfb = cf + (size_t)b * kNCH * kDM;
  float a0 = 0.f, a1 = 0.f, a2 = 0.f, a3 = 0.f;
#pragma unroll 4
  for (int ncc = 0; ncc < kNCH; ncc += 4) {
    a0 = fmaf(wl[ncc + 0], cfb[(ncc + 0) * kDM + tid], a0);
    a1 = fmaf(wl[ncc + 1], cfb[(ncc + 1) * kDM + tid], a1);
    a2 = fmaf(wl[ncc + 2], cfb[(ncc + 2) * kDM + tid], a2);
    a3 = fmaf(wl[ncc + 3], cfb[(ncc + 3) * kDM + tid], a3);
  }
  rep[tid] = ((a0 + a1) + (a2 + a3)) * inv;
  __syncthreads();

  if (tid < 64) {
    float acc = cl1_b[tid];
    const float4* rp = (const float4*)rep;
#pragma unroll 8
    for (int q = 0; q < 32; ++q) {
      float4 v = rp[q];
      acc = fmaf(v.x, cl1_w[(q * 4 + 0) * 64 + tid], acc);
      acc = fmaf(v.y, cl1_w[(q * 4 + 1) * 64 + tid], acc);
      acc = fmaf(v.z, cl1_w[(q * 4 + 2) * 64 + tid], acc);
      acc = fmaf(v.w, cl1_w[(q * 4 + 3) * 64 + tid], acc);
    }
    ul[tid] = fast_silu(acc);
  }
  __syncthreads();

  if (tid < 2) {
    float acc = cl2_b[tid];
#pragma unroll
    for (int k = 0; k < 64; ++k) acc = fmaf(ul[k], cl2_w[k * 2 + tid], acc);
    out[b * 2 + tid] = acc;
  }
}

// ---------------------------------------------------------------------------

extern "C" void kernel_launch(void* const* d_in, const int* in_sizes, int n_in,
                              void* d_out, int out_size, void* d_ws, size_t ws_size,
                              hipStream_t stream) {
  const float* x      = (const float*)d_in[0];
  const float* conv_w = (const float*)d_in[1];
  const float* conv_b = (const float*)d_in[2];
  const float* ln1_g  = (const float*)d_in[3];
  const float* ln1_b  = (const float*)d_in[4];
  const float* ca1_w  = (const float*)d_in[5];
  const float* ca1_b  = (const float*)d_in[6];
  const float* ca2_w  = (const float*)d_in[7];
  const float* ca2_b  = (const float*)d_in[8];
  const float* pp_w   = (const float*)d_in[9];
  const float* pp_b   = (const float*)d_in[10];
  const float* ep_w   = (const float*)d_in[11];
  const float* ep_b   = (const float*)d_in[12];
  const float* op_w   = (const float*)d_in[13];
  const float* op_b   = (const float*)d_in[14];
  const float* ln2_g  = (const float*)d_in[15];
  const float* ln2_b  = (const float*)d_in[16];
  const float* sa1_w  = (const float*)d_in[17];
  const float* sa1_b  = (const float*)d_in[18];
  const float* sa2_w  = (const float*)d_in[19];
  const float* sa2_b  = (const float*)d_in[20];
  const float* cl1_w  = (const float*)d_in[21];
  const float* cl1_b  = (const float*)d_in[22];
  const float* cl2_w  = (const float*)d_in[23];
  const float* cl2_b  = (const float*)d_in[24];
  float* out = (float*)d_out;
  float* cf  = (float*)d_ws;                               // 16384*128 f32 = 8 MB
  float* scl = (float*)d_ws + (size_t)kBATCH * kNCH * kDM; // 16384 f32

  k_chunk<<<kBATCH * kNCH, 128, 0, stream>>>(
      x, conv_w, conv_b, ln1_g, ln1_b, ca1_w, ca1_b, ca2_w, ca2_b,
      pp_w, pp_b, ep_w, ep_b, op_w, op_b, ln2_g, ln2_b, cf);
  k_scl<<<(kBATCH * kNCH) / 4, 256, 0, stream>>>(
      cf, sa1_w, sa1_b, sa2_w, sa2_b, scl);
  k_pool<<<kBATCH, 128, 0, stream>>>(
      cf, scl, cl1_w, cl1_b, cl2_w, cl2_b, out);
}